// Round 1
// baseline (272.741 us; speedup 1.0000x reference)
//
#include <hip/hip_runtime.h>
#include <math.h>

#define T_ 512

typedef _Float16 half8 __attribute__((ext_vector_type(8)));
typedef _Float16 half4 __attribute__((ext_vector_type(4)));
typedef float f32x4 __attribute__((ext_vector_type(4)));

// tanh(a)*sigmoid(b) = ((e^2a - 1) * e^b) / ((e^2a + 1) * (e^b + 1))
// single raw v_rcp instead of two full-precision divides.
__device__ __forceinline__ float ts_act(float a, float b) {
    float e2a = __expf(a + a);
    float eb  = __expf(b);
    float num = (e2a - 1.0f) * eb;
    float den = (e2a + 1.0f) * (eb + 1.0f);
    return num * __builtin_amdgcn_rcpf(den);
}

__device__ __forceinline__ half4 pack4(f32x4 v) {
    half4 h;
    h[0] = (_Float16)v[0]; h[1] = (_Float16)v[1];
    h[2] = (_Float16)v[2]; h[3] = (_Float16)v[3];
    return h;
}

// ---------------------------------------------------------------------------
// Prep fragment buffers in d_ws.
//  AF  [16384 f16] : adjacency, frag((it*4+kt))[lane][j] = A[it*16+(L&15)][kt*32+(L>>4)*8+j]
//  W32 [ 8192 f16] : K=32 folded conv mats (l*2+branch), 0..7
//                    frag idx (mat*2+ct)*64+L, slot j: W[k=(L>>4)*8+j][ct*16+(L&15)]
//  W16 [15360 f16] : K=16 mats: l*3+{0:gw,1:rw,2:sw} (0..11), 12:w1, 13:w2(pad), 14:winit16
//                    frag idx (mat*4+ks*2+ct)*64+L, slot i: W[ks*16+(L>>4)*4+i][ct*16+(L&15)]
//  BIAS[512 f32]   : pv-resolved conv biases: [(l*2+pv)*2+br]*32+n
// total idx = 16384+8192+15360+512 = 40448 = 158*256 (bytes: 79872 + 2048 = 81920)
// ---------------------------------------------------------------------------
__global__ __launch_bounds__(256) void k_prep(
    const float* __restrict__ A,     const float* __restrict__ in_w,
    const float* __restrict__ in_b,
    const float* __restrict__ ct_w,  const float* __restrict__ ct_b,
    const float* __restrict__ cs_w,  const float* __restrict__ cs_b,
    const float* __restrict__ gcn_w, const float* __restrict__ res_w,
    const float* __restrict__ skip_w,
    const float* __restrict__ out1_w,const float* __restrict__ out2_w,
    _Float16* __restrict__ FR, float* __restrict__ BIAS)
{
    int idx = blockIdx.x * 256 + threadIdx.x;
    if (idx < 16384) {
        int j = idx & 7, L = (idx >> 3) & 63, tile = idx >> 9;
        int it = tile >> 2, kt = tile & 3;
        FR[idx] = (_Float16)A[(it * 16 + (L & 15)) * 128 + kt * 32 + (L >> 4) * 8 + j];
    } else if (idx < 24576) {
        int e = idx - 16384;
        int j = e & 7, L = (e >> 3) & 63, ct = (e >> 9) & 1, mat = e >> 10;   // 0..7
        int k = (L >> 4) * 8 + j, col = ct * 16 + (L & 15);
        int l = mat >> 1, br = mat & 1;
        const float* tw = (br ? cs_w : ct_w) + l * 2048;
        int bro = br * 32;
        float v = 0.f;
        if (k < 16) { for (int c = 0; c < 32; ++c) v += in_w[k*96 + bro + c] * tw[c*32 + col]; }
        else        { for (int c = 0; c < 32; ++c) v += in_w[(k-16)*96 + bro + c] * tw[1024 + c*32 + col]; }
        FR[idx] = (_Float16)v;
    } else if (idx < 39936) {
        int e = idx - 24576;
        int i = e & 3, L = (e >> 2) & 63, ct = (e >> 8) & 1, ks = (e >> 9) & 1, mat = e >> 10; // 0..14
        int k = ks * 16 + (L >> 4) * 4 + i, col = ct * 16 + (L & 15);
        float v;
        if (mat < 12) {
            int l = mat / 3, r = mat - l * 3;
            const float* W = (r == 0) ? gcn_w : (r == 1) ? res_w : skip_w;
            v = W[l * 1024 + k * 32 + col];
        } else if (mat == 12) v = out1_w[k * 32 + col];
        else if (mat == 13)   v = (ct == 0) ? out2_w[k * 16 + (L & 15)] : 0.f;
        else                  v = (ks == 0) ? in_w[k * 96 + 64 + col] : 0.f;   // winit K=16
        FR[idx] = (_Float16)v;
    } else if (idx < 40448) {
        // pv-resolved conv biases: e = l*128 + pvi*64 + br*32 + n
        int e = idx - 39936;
        int n = e & 31, br = (e >> 5) & 1, pvi = (e >> 6) & 1, l = e >> 7;
        const float* W  = br ? cs_w : ct_w;
        const float* bb = br ? cs_b : ct_b;
        int ibo = br * 32;
        float v = bb[l * 32 + n];
        for (int c = 0; c < 32; ++c) v += in_b[ibo + c] * W[l*2048 + 1024 + c*32 + n]; // cur tap
        if (pvi)
            for (int c = 0; c < 32; ++c) v += in_b[ibo + c] * W[l*2048 + c*32 + n];    // prev tap
        BIAS[e] = v;
    }
}

// ---------------------------------------------------------------------------
// Fused net. One block per (b,t), XCD-swizzled so XCD j owns batch j (X slab
// fits its 4MB L2). All biases ride MFMA C operands; adjacency frags hoisted;
// winit done K=16 straight from registers (no first LDS staging).
// ---------------------------------------------------------------------------
__global__ __launch_bounds__(256, 4) void k_fused(
    const float* __restrict__ X,
    const _Float16* __restrict__ FR,
    const float* __restrict__ BIAS,
    const float* __restrict__ in_b,
    const float* __restrict__ gcn_b,
    const float* __restrict__ res_b,
    const float* __restrict__ skip_b,
    const float* __restrict__ b1,
    const float* __restrict__ b2,
    float* __restrict__ out)
{
    __shared__ _Float16 Pld[128 * 40];        // [node][prev16|cur16|pad8]
    __shared__ _Float16 xsT[2][32 * 136];     // [chan][node(128)+pad8], ping-pong

    const int bx = blockIdx.x;
    const int btid = ((bx & 7) << 9) | (bx >> 3);   // XCD j <- batch j
    const int b = btid >> 9, t = btid & (T_ - 1);
    const int tid = threadIdx.x, lane = tid & 63, w = tid >> 6;
    const int lm = lane & 15, kb = lane >> 4;
    const int R = w * 32;

    const half8* AFv  = (const half8*)FR;
    const half8* W32v = (const half8*)(FR + 16384);
    const half4* W16v = (const half4*)(FR + 24576);
    const f32x4 zero4 = {0.f, 0.f, 0.f, 0.f};

    const int row = lane >> 1, ch = lane & 1;

    // ---- hoisted adjacency fragments (layer-invariant, 32 VGPRs) ----
    half8 Afr[2][4];
#pragma unroll
    for (int mt = 0; mt < 2; ++mt)
#pragma unroll
        for (int kt = 0; kt < 4; ++kt)
            Afr[mt][kt] = AFv[((w * 2 + mt) * 4 + kt) * 64 + lane];

    // ---- xres init: K=16 MFMA straight from registers (true coords) ----
    f32x4 xm[2][2], skT[2][2];
    {
        const float4 x0 = *(const float4*)(X + ((size_t)btid * 128 + R + lm) * 16 + kb * 4);
        const float4 x1 = *(const float4*)(X + ((size_t)btid * 128 + R + 16 + lm) * 16 + kb * 4);
        half4 p0, p1;
        p0[0]=(_Float16)x0.x; p0[1]=(_Float16)x0.y; p0[2]=(_Float16)x0.z; p0[3]=(_Float16)x0.w;
        p1[0]=(_Float16)x1.x; p1[1]=(_Float16)x1.y; p1[2]=(_Float16)x1.z; p1[3]=(_Float16)x1.w;
#pragma unroll
        for (int f = 0; f < 2; ++f) {
            half4 wi = W16v[(56 + f) * 64 + lane];          // winit mat 14, ks=0
            float bi = in_b[64 + f * 16 + lm];
            f32x4 cb; cb[0] = bi; cb[1] = bi; cb[2] = bi; cb[3] = bi;
            xm[0][f] = __builtin_amdgcn_mfma_f32_16x16x16f16(p0, wi, cb, 0, 0, 0);
            xm[1][f] = __builtin_amdgcn_mfma_f32_16x16x16f16(p1, wi, cb, 0, 0, 0);
        }
        // skip accumulator starts at sum_l skip_b (replaces per-layer adds)
#pragma unroll
        for (int f3 = 0; f3 < 2; ++f3) {
            f32x4 s = zero4;
#pragma unroll
            for (int l = 0; l < 4; ++l) {
                const float4 q = *(const float4*)&skip_b[l * 32 + f3 * 16 + kb * 4];
                s[0] += q.x; s[1] += q.y; s[2] += q.z; s[3] += q.w;
            }
            skT[f3][0] = s; skT[f3][1] = s;
        }
    }

    // ---- stage cur conv slab (conv coords) ----
    {
        const float4* s4 = (const float4*)(X + ((size_t)(b * 128 + R + row) * T_ + t) * 16 + ch * 8);
        float4 u0 = s4[0], u1 = s4[1];
        half8 hv;
        hv[0]=(_Float16)u0.x; hv[1]=(_Float16)u0.y; hv[2]=(_Float16)u0.z; hv[3]=(_Float16)u0.w;
        hv[4]=(_Float16)u1.x; hv[5]=(_Float16)u1.y; hv[6]=(_Float16)u1.z; hv[7]=(_Float16)u1.w;
        *(half8*)&Pld[(R + row) * 40 + 16 + ch * 8] = hv;
    }

#pragma unroll 1
    for (int l = 0; l < 4; ++l) {
        const int d = 1 << l;
        const bool pv = (t >= d);                 // block-uniform
        const float* B2 = BIAS + (l * 2 + (pv ? 1 : 0)) * 64;

        // ---- stage prev slab (conv coords), zeros if t<d ----
        {
            half8 hv = {0,0,0,0,0,0,0,0};
            if (pv) {
                const float4* s4 = (const float4*)(X + ((size_t)(b * 128 + R + row) * T_ + (t - d)) * 16 + ch * 8);
                float4 u0 = s4[0], u1 = s4[1];
                hv[0]=(_Float16)u0.x; hv[1]=(_Float16)u0.y; hv[2]=(_Float16)u0.z; hv[3]=(_Float16)u0.w;
                hv[4]=(_Float16)u1.x; hv[5]=(_Float16)u1.y; hv[6]=(_Float16)u1.z; hv[7]=(_Float16)u1.w;
            }
            *(half8*)&Pld[(R + row) * 40 + ch * 8] = hv;
        }

        // ---- conv (transposed): biases ride C operands ----
        half8 pf0 = *(const half8*)&Pld[(R + lm) * 40 + kb * 8];
        half8 pf1 = *(const half8*)&Pld[(R + 16 + lm) * 40 + kb * 8];
        f32x4 tcv[2][2];                          // [ct][mt]
#pragma unroll
        for (int ct = 0; ct < 2; ++ct) {
            half8 wt = W32v[((l * 2 + 0) * 2 + ct) * 64 + lane];
            half8 ws = W32v[((l * 2 + 1) * 2 + ct) * 64 + lane];
            const f32x4 cT = *(const f32x4*)&B2[ct * 16 + kb * 4];
            const f32x4 cS = *(const f32x4*)&B2[32 + ct * 16 + kb * 4];
            f32x4 dt0 = __builtin_amdgcn_mfma_f32_16x16x32_f16(wt, pf0, cT, 0, 0, 0);
            f32x4 dt1 = __builtin_amdgcn_mfma_f32_16x16x32_f16(wt, pf1, cT, 0, 0, 0);
            f32x4 ds0 = __builtin_amdgcn_mfma_f32_16x16x32_f16(ws, pf0, cS, 0, 0, 0);
            f32x4 ds1 = __builtin_amdgcn_mfma_f32_16x16x32_f16(ws, pf1, cS, 0, 0, 0);
#pragma unroll
            for (int r = 0; r < 4; ++r) {
                tcv[ct][0][r] = ts_act(dt0[r], ds0[r]);
                tcv[ct][1][r] = ts_act(dt1[r], ds1[r]);
            }
        }

        // ---- publish xres (normal D -> chan-major LDS) ----
        const int buf = l & 1;
#pragma unroll
        for (int mt = 0; mt < 2; ++mt)
#pragma unroll
            for (int f = 0; f < 2; ++f)
                *(half4*)&xsT[buf][(f * 16 + lm) * 136 + R + mt * 16 + kb * 4] = pack4(xm[mt][f]);
        __syncthreads();

        // ---- A-mix: AxT[c][i] — A = xres^T frags (LDS), B = hoisted A frags ----
        f32x4 AxT[2][2];                          // [f][mt]
#pragma unroll
        for (int f = 0; f < 2; ++f) {
            half8 xa[4];
#pragma unroll
            for (int kt = 0; kt < 4; ++kt)
                xa[kt] = *(const half8*)&xsT[buf][(f * 16 + lm) * 136 + kt * 32 + kb * 8];
#pragma unroll
            for (int mt = 0; mt < 2; ++mt) {
                f32x4 acc = zero4;
#pragma unroll
                for (int kt = 0; kt < 4; ++kt)
                    acc = __builtin_amdgcn_mfma_f32_16x16x32_f16(xa[kt], Afr[mt][kt], acc, 0, 0, 0);
                AxT[f][mt] = acc;
            }
        }

        // ---- gcn_T: gcn_b rides C; add tcv after ----
        half4 axh[2][2];
#pragma unroll
        for (int f = 0; f < 2; ++f)
#pragma unroll
            for (int mt = 0; mt < 2; ++mt) axh[f][mt] = pack4(AxT[f][mt]);
        half4 hh[2][2];                           // h_T packed [g][mt]
#pragma unroll
        for (int g = 0; g < 2; ++g) {
            half4 gw0 = W16v[((l * 3 + 0) * 4 + 0 + g) * 64 + lane];
            half4 gw1 = W16v[((l * 3 + 0) * 4 + 2 + g) * 64 + lane];
            const f32x4 gq = *(const f32x4*)&gcn_b[l * 32 + g * 16 + kb * 4];
#pragma unroll
            for (int mt = 0; mt < 2; ++mt) {
                f32x4 acc = __builtin_amdgcn_mfma_f32_16x16x16f16(gw0, axh[0][mt], gq, 0, 0, 0);
                acc = __builtin_amdgcn_mfma_f32_16x16x16f16(gw1, axh[1][mt], acc, 0, 0, 0);
#pragma unroll
                for (int r = 0; r < 4; ++r) acc[r] += tcv[g][mt][r];
                hh[g][mt] = pack4(acc);
            }
        }

        // ---- res (normal) & skip_T (bias pre-folded into skT init) ----
#pragma unroll
        for (int mt = 0; mt < 2; ++mt)
#pragma unroll
            for (int f3 = 0; f3 < 2; ++f3) {
                half4 rw0 = W16v[((l * 3 + 1) * 4 + 0 + f3) * 64 + lane];
                half4 rw1 = W16v[((l * 3 + 1) * 4 + 2 + f3) * 64 + lane];
                f32x4 acc = __builtin_amdgcn_mfma_f32_16x16x16f16(hh[0][mt], rw0, xm[mt][f3], 0, 0, 0);
                xm[mt][f3] = __builtin_amdgcn_mfma_f32_16x16x16f16(hh[1][mt], rw1, acc, 0, 0, 0);
                float rb = res_b[l * 32 + f3 * 16 + lm];
#pragma unroll
                for (int r = 0; r < 4; ++r) xm[mt][f3][r] += rb;

                half4 sw0 = W16v[((l * 3 + 2) * 4 + 0 + f3) * 64 + lane];
                half4 sw1 = W16v[((l * 3 + 2) * 4 + 2 + f3) * 64 + lane];
                f32x4 acs = __builtin_amdgcn_mfma_f32_16x16x16f16(sw0, hh[0][mt], skT[f3][mt], 0, 0, 0);
                skT[f3][mt] = __builtin_amdgcn_mfma_f32_16x16x16f16(sw1, hh[1][mt], acs, 0, 0, 0);
            }
    }

    // ---- output head (biases ride C operands) ----
    half4 rs[2][2];
#pragma unroll
    for (int g = 0; g < 2; ++g)
#pragma unroll
        for (int mt = 0; mt < 2; ++mt) {
            f32x4 v;
#pragma unroll
            for (int r = 0; r < 4; ++r) v[r] = fmaxf(skT[g][mt][r], 0.f);
            rs[g][mt] = pack4(v);
        }
    half4 h1h[2][2];
#pragma unroll
    for (int g4 = 0; g4 < 2; ++g4) {
        half4 w10 = W16v[(48 + 0 + g4) * 64 + lane];
        half4 w11 = W16v[(48 + 2 + g4) * 64 + lane];
        const f32x4 bq = *(const f32x4*)&b1[g4 * 16 + kb * 4];
#pragma unroll
        for (int mt = 0; mt < 2; ++mt) {
            f32x4 acc = __builtin_amdgcn_mfma_f32_16x16x16f16(w10, rs[0][mt], bq, 0, 0, 0);
            acc = __builtin_amdgcn_mfma_f32_16x16x16f16(w11, rs[1][mt], acc, 0, 0, 0);
            f32x4 v;
#pragma unroll
            for (int r = 0; r < 4; ++r) v[r] = fmaxf(acc[r], 0.f);
            h1h[g4][mt] = pack4(v);
        }
    }
    {
        half4 w20 = W16v[(52 + 0) * 64 + lane];
        half4 w21 = W16v[(52 + 2) * 64 + lane];
        const f32x4 b2q = *(const f32x4*)&b2[kb * 4];
#pragma unroll
        for (int mt = 0; mt < 2; ++mt) {
            f32x4 acc = __builtin_amdgcn_mfma_f32_16x16x16f16(w20, h1h[0][mt], b2q, 0, 0, 0);
            acc = __builtin_amdgcn_mfma_f32_16x16x16f16(w21, h1h[1][mt], acc, 0, 0, 0);
            float4 o = make_float4(acc[0], acc[1], acc[2], acc[3]);
            *(float4*)&out[((size_t)btid * 128 + R + mt * 16 + lm) * 16 + kb * 4] = o;
        }
    }
}

// ---------------------------------------------------------------------------
extern "C" void kernel_launch(void* const* d_in, const int* in_sizes, int n_in,
                              void* d_out, int out_size, void* d_ws, size_t ws_size,
                              hipStream_t stream)
{
    const float* X      = (const float*)d_in[0];
    const float* A      = (const float*)d_in[1];
    const float* in_w   = (const float*)d_in[2];
    const float* in_b   = (const float*)d_in[3];
    const float* ct_w   = (const float*)d_in[4];
    const float* ct_b   = (const float*)d_in[5];
    const float* cs_w   = (const float*)d_in[6];
    const float* cs_b   = (const float*)d_in[7];
    const float* gcn_w  = (const float*)d_in[8];
    const float* gcn_b  = (const float*)d_in[9];
    const float* res_w  = (const float*)d_in[10];
    const float* res_b  = (const float*)d_in[11];
    const float* skip_w = (const float*)d_in[12];
    const float* skip_b = (const float*)d_in[13];
    const float* out1_w = (const float*)d_in[14];
    const float* out1_b = (const float*)d_in[15];
    const float* out2_w = (const float*)d_in[16];
    const float* out2_b = (const float*)d_in[17];

    _Float16* FR   = (_Float16*)d_ws;                 // 39936 f16 = 79872 B
    float*    BIAS = (float*)((char*)d_ws + 79872);   // 512 f32

    k_prep<<<158, 256, 0, stream>>>(A, in_w, in_b, ct_w, ct_b, cs_w, cs_b,
                                    gcn_w, res_w, skip_w, out1_w, out2_w,
                                    FR, BIAS);

    k_fused<<<8 * T_, 256, 0, stream>>>(X, FR, BIAS, in_b,
                                        gcn_b, res_b, skip_b,
                                        out1_b, out2_b, (float*)d_out);
}

// Round 2
// 198.463 us; speedup vs baseline: 1.3743x; 1.3743x over previous
//
#include <hip/hip_runtime.h>
#include <math.h>

#define T_ 512

typedef _Float16 half8 __attribute__((ext_vector_type(8)));
typedef _Float16 half4 __attribute__((ext_vector_type(4)));
typedef float f32x4 __attribute__((ext_vector_type(4)));

// tanh(a)*sigmoid(b) = ((e^2a - 1) * e^b) / ((e^2a + 1) * (e^b + 1))
// single raw v_rcp instead of two full-precision divides.
__device__ __forceinline__ float ts_act(float a, float b) {
    float e2a = __expf(a + a);
    float eb  = __expf(b);
    float num = (e2a - 1.0f) * eb;
    float den = (e2a + 1.0f) * (eb + 1.0f);
    return num * __builtin_amdgcn_rcpf(den);
}

__device__ __forceinline__ half4 pack4(f32x4 v) {
    half4 h;
    h[0] = (_Float16)v[0]; h[1] = (_Float16)v[1];
    h[2] = (_Float16)v[2]; h[3] = (_Float16)v[3];
    return h;
}

// ---------------------------------------------------------------------------
// Prep fragment buffers in d_ws.
//  AF  [16384 f16] : adjacency, frag((it*4+kt))[lane][j] = A[it*16+(L&15)][kt*32+(L>>4)*8+j]
//  W32 [ 8192 f16] : K=32 folded conv mats (l*2+branch), 0..7
//                    frag idx (mat*2+ct)*64+L, slot j: W[k=(L>>4)*8+j][ct*16+(L&15)]
//  W16 [15360 f16] : K=16 mats: l*3+{0:gw,1:rw,2:sw} (0..11), 12:w1, 13:w2(pad), 14:winit16
//                    frag idx (mat*4+ks*2+ct)*64+L, slot i: W[ks*16+(L>>4)*4+i][ct*16+(L&15)]
//  BIAS[512 f32]   : pv-resolved conv biases: [(l*2+pv)*2+br]*32+n
// total idx = 16384+8192+15360+512 = 40448 = 158*256 (bytes: 79872 + 2048 = 81920)
// ---------------------------------------------------------------------------
__global__ __launch_bounds__(256) void k_prep(
    const float* __restrict__ A,     const float* __restrict__ in_w,
    const float* __restrict__ in_b,
    const float* __restrict__ ct_w,  const float* __restrict__ ct_b,
    const float* __restrict__ cs_w,  const float* __restrict__ cs_b,
    const float* __restrict__ gcn_w, const float* __restrict__ res_w,
    const float* __restrict__ skip_w,
    const float* __restrict__ out1_w,const float* __restrict__ out2_w,
    _Float16* __restrict__ FR, float* __restrict__ BIAS)
{
    int idx = blockIdx.x * 256 + threadIdx.x;
    if (idx < 16384) {
        int j = idx & 7, L = (idx >> 3) & 63, tile = idx >> 9;
        int it = tile >> 2, kt = tile & 3;
        FR[idx] = (_Float16)A[(it * 16 + (L & 15)) * 128 + kt * 32 + (L >> 4) * 8 + j];
    } else if (idx < 24576) {
        int e = idx - 16384;
        int j = e & 7, L = (e >> 3) & 63, ct = (e >> 9) & 1, mat = e >> 10;   // 0..7
        int k = (L >> 4) * 8 + j, col = ct * 16 + (L & 15);
        int l = mat >> 1, br = mat & 1;
        const float* tw = (br ? cs_w : ct_w) + l * 2048;
        int bro = br * 32;
        float v = 0.f;
        if (k < 16) { for (int c = 0; c < 32; ++c) v += in_w[k*96 + bro + c] * tw[c*32 + col]; }
        else        { for (int c = 0; c < 32; ++c) v += in_w[(k-16)*96 + bro + c] * tw[1024 + c*32 + col]; }
        FR[idx] = (_Float16)v;
    } else if (idx < 39936) {
        int e = idx - 24576;
        int i = e & 3, L = (e >> 2) & 63, ct = (e >> 8) & 1, ks = (e >> 9) & 1, mat = e >> 10; // 0..14
        int k = ks * 16 + (L >> 4) * 4 + i, col = ct * 16 + (L & 15);
        float v;
        if (mat < 12) {
            int l = mat / 3, r = mat - l * 3;
            const float* W = (r == 0) ? gcn_w : (r == 1) ? res_w : skip_w;
            v = W[l * 1024 + k * 32 + col];
        } else if (mat == 12) v = out1_w[k * 32 + col];
        else if (mat == 13)   v = (ct == 0) ? out2_w[k * 16 + (L & 15)] : 0.f;
        else                  v = (ks == 0) ? in_w[k * 96 + 64 + col] : 0.f;   // winit K=16
        FR[idx] = (_Float16)v;
    } else if (idx < 40448) {
        // pv-resolved conv biases: e = l*128 + pvi*64 + br*32 + n
        int e = idx - 39936;
        int n = e & 31, br = (e >> 5) & 1, pvi = (e >> 6) & 1, l = e >> 7;
        const float* W  = br ? cs_w : ct_w;
        const float* bb = br ? cs_b : ct_b;
        int ibo = br * 32;
        float v = bb[l * 32 + n];
        for (int c = 0; c < 32; ++c) v += in_b[ibo + c] * W[l*2048 + 1024 + c*32 + n]; // cur tap
        if (pvi)
            for (int c = 0; c < 32; ++c) v += in_b[ibo + c] * W[l*2048 + c*32 + n];    // prev tap
        BIAS[e] = v;
    }
}

// ---------------------------------------------------------------------------
// Fused net. One block per (b,t), XCD-swizzled so XCD j owns batch j (X slab
// fits its 4MB L2). All biases ride MFMA C operands; winit done K=16 straight
// from registers (no first LDS staging). Adjacency frags loaded per layer
// (NOT hoisted — hoisting triggered the allocator's spill tier in R1).
// ---------------------------------------------------------------------------
__global__ __launch_bounds__(256, 3) void k_fused(
    const float* __restrict__ X,
    const _Float16* __restrict__ FR,
    const float* __restrict__ BIAS,
    const float* __restrict__ in_b,
    const float* __restrict__ gcn_b,
    const float* __restrict__ res_b,
    const float* __restrict__ skip_b,
    const float* __restrict__ b1,
    const float* __restrict__ b2,
    float* __restrict__ out)
{
    __shared__ _Float16 Pld[128 * 40];        // [node][prev16|cur16|pad8]
    __shared__ _Float16 xsT[2][32 * 136];     // [chan][node(128)+pad8], ping-pong

    const int bx = blockIdx.x;
    const int btid = ((bx & 7) << 9) | (bx >> 3);   // XCD j <- batch j
    const int b = btid >> 9, t = btid & (T_ - 1);
    const int tid = threadIdx.x, lane = tid & 63, w = tid >> 6;
    const int lm = lane & 15, kb = lane >> 4;
    const int R = w * 32;

    const half8* AFv  = (const half8*)FR;
    const half8* W32v = (const half8*)(FR + 16384);
    const half4* W16v = (const half4*)(FR + 24576);
    const f32x4 zero4 = {0.f, 0.f, 0.f, 0.f};

    const int row = lane >> 1, ch = lane & 1;

    // ---- xres init: K=16 MFMA straight from registers (true coords) ----
    f32x4 xm[2][2], skT[2][2];
    {
        const float4 x0 = *(const float4*)(X + ((size_t)btid * 128 + R + lm) * 16 + kb * 4);
        const float4 x1 = *(const float4*)(X + ((size_t)btid * 128 + R + 16 + lm) * 16 + kb * 4);
        half4 p0, p1;
        p0[0]=(_Float16)x0.x; p0[1]=(_Float16)x0.y; p0[2]=(_Float16)x0.z; p0[3]=(_Float16)x0.w;
        p1[0]=(_Float16)x1.x; p1[1]=(_Float16)x1.y; p1[2]=(_Float16)x1.z; p1[3]=(_Float16)x1.w;
#pragma unroll
        for (int f = 0; f < 2; ++f) {
            half4 wi = W16v[(56 + f) * 64 + lane];          // winit mat 14, ks=0
            float bi = in_b[64 + f * 16 + lm];
            f32x4 cb; cb[0] = bi; cb[1] = bi; cb[2] = bi; cb[3] = bi;
            xm[0][f] = __builtin_amdgcn_mfma_f32_16x16x16f16(p0, wi, cb, 0, 0, 0);
            xm[1][f] = __builtin_amdgcn_mfma_f32_16x16x16f16(p1, wi, cb, 0, 0, 0);
        }
        // skip accumulator starts at sum_l skip_b (replaces per-layer adds)
#pragma unroll
        for (int f3 = 0; f3 < 2; ++f3) {
            f32x4 s = zero4;
#pragma unroll
            for (int l = 0; l < 4; ++l) {
                const float4 q = *(const float4*)&skip_b[l * 32 + f3 * 16 + kb * 4];
                s[0] += q.x; s[1] += q.y; s[2] += q.z; s[3] += q.w;
            }
            skT[f3][0] = s; skT[f3][1] = s;
        }
    }

    // ---- stage cur conv slab (conv coords) ----
    {
        const float4* s4 = (const float4*)(X + ((size_t)(b * 128 + R + row) * T_ + t) * 16 + ch * 8);
        float4 u0 = s4[0], u1 = s4[1];
        half8 hv;
        hv[0]=(_Float16)u0.x; hv[1]=(_Float16)u0.y; hv[2]=(_Float16)u0.z; hv[3]=(_Float16)u0.w;
        hv[4]=(_Float16)u1.x; hv[5]=(_Float16)u1.y; hv[6]=(_Float16)u1.z; hv[7]=(_Float16)u1.w;
        *(half8*)&Pld[(R + row) * 40 + 16 + ch * 8] = hv;
    }

#pragma unroll 1
    for (int l = 0; l < 4; ++l) {
        const int d = 1 << l;
        const bool pv = (t >= d);                 // block-uniform
        const float* B2 = BIAS + (l * 2 + (pv ? 1 : 0)) * 64;

        // ---- stage prev slab (conv coords), zeros if t<d ----
        {
            half8 hv = {0,0,0,0,0,0,0,0};
            if (pv) {
                const float4* s4 = (const float4*)(X + ((size_t)(b * 128 + R + row) * T_ + (t - d)) * 16 + ch * 8);
                float4 u0 = s4[0], u1 = s4[1];
                hv[0]=(_Float16)u0.x; hv[1]=(_Float16)u0.y; hv[2]=(_Float16)u0.z; hv[3]=(_Float16)u0.w;
                hv[4]=(_Float16)u1.x; hv[5]=(_Float16)u1.y; hv[6]=(_Float16)u1.z; hv[7]=(_Float16)u1.w;
            }
            *(half8*)&Pld[(R + row) * 40 + ch * 8] = hv;
        }

        // ---- conv (transposed): biases ride C operands ----
        half8 pf0 = *(const half8*)&Pld[(R + lm) * 40 + kb * 8];
        half8 pf1 = *(const half8*)&Pld[(R + 16 + lm) * 40 + kb * 8];
        f32x4 tcv[2][2];                          // [ct][mt]
#pragma unroll
        for (int ct = 0; ct < 2; ++ct) {
            half8 wt = W32v[((l * 2 + 0) * 2 + ct) * 64 + lane];
            half8 ws = W32v[((l * 2 + 1) * 2 + ct) * 64 + lane];
            const f32x4 cT = *(const f32x4*)&B2[ct * 16 + kb * 4];
            const f32x4 cS = *(const f32x4*)&B2[32 + ct * 16 + kb * 4];
            f32x4 dt0 = __builtin_amdgcn_mfma_f32_16x16x32_f16(wt, pf0, cT, 0, 0, 0);
            f32x4 dt1 = __builtin_amdgcn_mfma_f32_16x16x32_f16(wt, pf1, cT, 0, 0, 0);
            f32x4 ds0 = __builtin_amdgcn_mfma_f32_16x16x32_f16(ws, pf0, cS, 0, 0, 0);
            f32x4 ds1 = __builtin_amdgcn_mfma_f32_16x16x32_f16(ws, pf1, cS, 0, 0, 0);
#pragma unroll
            for (int r = 0; r < 4; ++r) {
                tcv[ct][0][r] = ts_act(dt0[r], ds0[r]);
                tcv[ct][1][r] = ts_act(dt1[r], ds1[r]);
            }
        }

        // ---- publish xres (normal D -> chan-major LDS) ----
        const int buf = l & 1;
#pragma unroll
        for (int mt = 0; mt < 2; ++mt)
#pragma unroll
            for (int f = 0; f < 2; ++f)
                *(half4*)&xsT[buf][(f * 16 + lm) * 136 + R + mt * 16 + kb * 4] = pack4(xm[mt][f]);
        __syncthreads();

        // ---- A-mix: AxT[c][i] — A = xres^T frags (LDS), B = adjacency frags ----
        f32x4 AxT[2][2];                          // [f][mt]
        half8 Afr[2][4];
#pragma unroll
        for (int mt = 0; mt < 2; ++mt)
#pragma unroll
            for (int kt = 0; kt < 4; ++kt)
                Afr[mt][kt] = AFv[((w * 2 + mt) * 4 + kt) * 64 + lane];
#pragma unroll
        for (int f = 0; f < 2; ++f) {
            half8 xa[4];
#pragma unroll
            for (int kt = 0; kt < 4; ++kt)
                xa[kt] = *(const half8*)&xsT[buf][(f * 16 + lm) * 136 + kt * 32 + kb * 8];
#pragma unroll
            for (int mt = 0; mt < 2; ++mt) {
                f32x4 acc = zero4;
#pragma unroll
                for (int kt = 0; kt < 4; ++kt)
                    acc = __builtin_amdgcn_mfma_f32_16x16x32_f16(xa[kt], Afr[mt][kt], acc, 0, 0, 0);
                AxT[f][mt] = acc;
            }
        }

        // ---- gcn_T: gcn_b rides C; add tcv after ----
        half4 axh[2][2];
#pragma unroll
        for (int f = 0; f < 2; ++f)
#pragma unroll
            for (int mt = 0; mt < 2; ++mt) axh[f][mt] = pack4(AxT[f][mt]);
        half4 hh[2][2];                           // h_T packed [g][mt]
#pragma unroll
        for (int g = 0; g < 2; ++g) {
            half4 gw0 = W16v[((l * 3 + 0) * 4 + 0 + g) * 64 + lane];
            half4 gw1 = W16v[((l * 3 + 0) * 4 + 2 + g) * 64 + lane];
            const f32x4 gq = *(const f32x4*)&gcn_b[l * 32 + g * 16 + kb * 4];
#pragma unroll
            for (int mt = 0; mt < 2; ++mt) {
                f32x4 acc = __builtin_amdgcn_mfma_f32_16x16x16f16(gw0, axh[0][mt], gq, 0, 0, 0);
                acc = __builtin_amdgcn_mfma_f32_16x16x16f16(gw1, axh[1][mt], acc, 0, 0, 0);
#pragma unroll
                for (int r = 0; r < 4; ++r) acc[r] += tcv[g][mt][r];
                hh[g][mt] = pack4(acc);
            }
        }

        // ---- res (normal) & skip_T (bias pre-folded into skT init) ----
#pragma unroll
        for (int mt = 0; mt < 2; ++mt)
#pragma unroll
            for (int f3 = 0; f3 < 2; ++f3) {
                half4 rw0 = W16v[((l * 3 + 1) * 4 + 0 + f3) * 64 + lane];
                half4 rw1 = W16v[((l * 3 + 1) * 4 + 2 + f3) * 64 + lane];
                f32x4 acc = __builtin_amdgcn_mfma_f32_16x16x16f16(hh[0][mt], rw0, xm[mt][f3], 0, 0, 0);
                xm[mt][f3] = __builtin_amdgcn_mfma_f32_16x16x16f16(hh[1][mt], rw1, acc, 0, 0, 0);
                float rb = res_b[l * 32 + f3 * 16 + lm];
#pragma unroll
                for (int r = 0; r < 4; ++r) xm[mt][f3][r] += rb;

                half4 sw0 = W16v[((l * 3 + 2) * 4 + 0 + f3) * 64 + lane];
                half4 sw1 = W16v[((l * 3 + 2) * 4 + 2 + f3) * 64 + lane];
                f32x4 acs = __builtin_amdgcn_mfma_f32_16x16x16f16(sw0, hh[0][mt], skT[f3][mt], 0, 0, 0);
                skT[f3][mt] = __builtin_amdgcn_mfma_f32_16x16x16f16(sw1, hh[1][mt], acs, 0, 0, 0);
            }
    }

    // ---- output head (biases ride C operands) ----
    half4 rs[2][2];
#pragma unroll
    for (int g = 0; g < 2; ++g)
#pragma unroll
        for (int mt = 0; mt < 2; ++mt) {
            f32x4 v;
#pragma unroll
            for (int r = 0; r < 4; ++r) v[r] = fmaxf(skT[g][mt][r], 0.f);
            rs[g][mt] = pack4(v);
        }
    half4 h1h[2][2];
#pragma unroll
    for (int g4 = 0; g4 < 2; ++g4) {
        half4 w10 = W16v[(48 + 0 + g4) * 64 + lane];
        half4 w11 = W16v[(48 + 2 + g4) * 64 + lane];
        const f32x4 bq = *(const f32x4*)&b1[g4 * 16 + kb * 4];
#pragma unroll
        for (int mt = 0; mt < 2; ++mt) {
            f32x4 acc = __builtin_amdgcn_mfma_f32_16x16x16f16(w10, rs[0][mt], bq, 0, 0, 0);
            acc = __builtin_amdgcn_mfma_f32_16x16x16f16(w11, rs[1][mt], acc, 0, 0, 0);
            f32x4 v;
#pragma unroll
            for (int r = 0; r < 4; ++r) v[r] = fmaxf(acc[r], 0.f);
            h1h[g4][mt] = pack4(v);
        }
    }
    {
        half4 w20 = W16v[(52 + 0) * 64 + lane];
        half4 w21 = W16v[(52 + 2) * 64 + lane];
        const f32x4 b2q = *(const f32x4*)&b2[kb * 4];
#pragma unroll
        for (int mt = 0; mt < 2; ++mt) {
            f32x4 acc = __builtin_amdgcn_mfma_f32_16x16x16f16(w20, h1h[0][mt], b2q, 0, 0, 0);
            acc = __builtin_amdgcn_mfma_f32_16x16x16f16(w21, h1h[1][mt], acc, 0, 0, 0);
            float4 o = make_float4(acc[0], acc[1], acc[2], acc[3]);
            *(float4*)&out[((size_t)btid * 128 + R + mt * 16 + lm) * 16 + kb * 4] = o;
        }
    }
}

// ---------------------------------------------------------------------------
extern "C" void kernel_launch(void* const* d_in, const int* in_sizes, int n_in,
                              void* d_out, int out_size, void* d_ws, size_t ws_size,
                              hipStream_t stream)
{
    const float* X      = (const float*)d_in[0];
    const float* A      = (const float*)d_in[1];
    const float* in_w   = (const float*)d_in[2];
    const float* in_b   = (const float*)d_in[3];
    const float* ct_w   = (const float*)d_in[4];
    const float* ct_b   = (const float*)d_in[5];
    const float* cs_w   = (const float*)d_in[6];
    const float* cs_b   = (const float*)d_in[7];
    const float* gcn_w  = (const float*)d_in[8];
    const float* gcn_b  = (const float*)d_in[9];
    const float* res_w  = (const float*)d_in[10];
    const float* res_b  = (const float*)d_in[11];
    const float* skip_w = (const float*)d_in[12];
    const float* skip_b = (const float*)d_in[13];
    const float* out1_w = (const float*)d_in[14];
    const float* out1_b = (const float*)d_in[15];
    const float* out2_w = (const float*)d_in[16];
    const float* out2_b = (const float*)d_in[17];

    _Float16* FR   = (_Float16*)d_ws;                 // 39936 f16 = 79872 B
    float*    BIAS = (float*)((char*)d_ws + 79872);   // 512 f32

    k_prep<<<158, 256, 0, stream>>>(A, in_w, in_b, ct_w, ct_b, cs_w, cs_b,
                                    gcn_w, res_w, skip_w, out1_w, out2_w,
                                    FR, BIAS);

    k_fused<<<8 * T_, 256, 0, stream>>>(X, FR, BIAS, in_b,
                                        gcn_b, res_b, skip_b,
                                        out1_b, out2_b, (float*)d_out);
}

// Round 3
// 195.553 us; speedup vs baseline: 1.3947x; 1.0149x over previous
//
#include <hip/hip_runtime.h>
#include <math.h>

#define T_ 512

typedef _Float16 half8 __attribute__((ext_vector_type(8)));
typedef _Float16 half4 __attribute__((ext_vector_type(4)));
typedef float f32x4 __attribute__((ext_vector_type(4)));

// tanh(a)*sigmoid(b) = ((e^2a - 1) * e^b) / ((e^2a + 1) * (e^b + 1))
// single raw v_rcp instead of two full-precision divides.
__device__ __forceinline__ float ts_act(float a, float b) {
    float e2a = __expf(a + a);
    float eb  = __expf(b);
    float num = (e2a - 1.0f) * eb;
    float den = (e2a + 1.0f) * (eb + 1.0f);
    return num * __builtin_amdgcn_rcpf(den);
}

__device__ __forceinline__ half4 pack4(f32x4 v) {
    half4 h;
    h[0] = (_Float16)v[0]; h[1] = (_Float16)v[1];
    h[2] = (_Float16)v[2]; h[3] = (_Float16)v[3];
    return h;
}

// ---------------------------------------------------------------------------
// Prep fragment buffers in d_ws.
//  AF  [16384 f16] : adjacency, frag((it*4+kt))[lane][j] = A[it*16+(L&15)][kt*32+(L>>4)*8+j]
//  W32 [ 8192 f16] : K=32 folded conv mats (l*2+branch), 0..7
//                    frag idx (mat*2+ct)*64+L, slot j: W[k=(L>>4)*8+j][ct*16+(L&15)]
//  W16 [15360 f16] : K=16 mats: l*3+{0:gw,1:rw,2:sw} (0..11), 12:w1, 13:w2(pad), 14:winit16
//                    frag idx (mat*4+ks*2+ct)*64+L, slot i: W[ks*16+(L>>4)*4+i][ct*16+(L&15)]
//  BIAS[512 f32]   : pv-resolved conv biases: [(l*2+pv)*2+br]*32+n
// total idx = 16384+8192+15360+512 = 40448 = 158*256 (bytes: 79872 + 2048 = 81920)
// ---------------------------------------------------------------------------
__global__ __launch_bounds__(256) void k_prep(
    const float* __restrict__ A,     const float* __restrict__ in_w,
    const float* __restrict__ in_b,
    const float* __restrict__ ct_w,  const float* __restrict__ ct_b,
    const float* __restrict__ cs_w,  const float* __restrict__ cs_b,
    const float* __restrict__ gcn_w, const float* __restrict__ res_w,
    const float* __restrict__ skip_w,
    const float* __restrict__ out1_w,const float* __restrict__ out2_w,
    _Float16* __restrict__ FR, float* __restrict__ BIAS)
{
    int idx = blockIdx.x * 256 + threadIdx.x;
    if (idx < 16384) {
        int j = idx & 7, L = (idx >> 3) & 63, tile = idx >> 9;
        int it = tile >> 2, kt = tile & 3;
        FR[idx] = (_Float16)A[(it * 16 + (L & 15)) * 128 + kt * 32 + (L >> 4) * 8 + j];
    } else if (idx < 24576) {
        int e = idx - 16384;
        int j = e & 7, L = (e >> 3) & 63, ct = (e >> 9) & 1, mat = e >> 10;   // 0..7
        int k = (L >> 4) * 8 + j, col = ct * 16 + (L & 15);
        int l = mat >> 1, br = mat & 1;
        const float* tw = (br ? cs_w : ct_w) + l * 2048;
        int bro = br * 32;
        float v = 0.f;
        if (k < 16) { for (int c = 0; c < 32; ++c) v += in_w[k*96 + bro + c] * tw[c*32 + col]; }
        else        { for (int c = 0; c < 32; ++c) v += in_w[(k-16)*96 + bro + c] * tw[1024 + c*32 + col]; }
        FR[idx] = (_Float16)v;
    } else if (idx < 39936) {
        int e = idx - 24576;
        int i = e & 3, L = (e >> 2) & 63, ct = (e >> 8) & 1, ks = (e >> 9) & 1, mat = e >> 10; // 0..14
        int k = ks * 16 + (L >> 4) * 4 + i, col = ct * 16 + (L & 15);
        float v;
        if (mat < 12) {
            int l = mat / 3, r = mat - l * 3;
            const float* W = (r == 0) ? gcn_w : (r == 1) ? res_w : skip_w;
            v = W[l * 1024 + k * 32 + col];
        } else if (mat == 12) v = out1_w[k * 32 + col];
        else if (mat == 13)   v = (ct == 0) ? out2_w[k * 16 + (L & 15)] : 0.f;
        else                  v = (ks == 0) ? in_w[k * 96 + 64 + col] : 0.f;   // winit K=16
        FR[idx] = (_Float16)v;
    } else if (idx < 40448) {
        // pv-resolved conv biases: e = l*128 + pvi*64 + br*32 + n
        int e = idx - 39936;
        int n = e & 31, br = (e >> 5) & 1, pvi = (e >> 6) & 1, l = e >> 7;
        const float* W  = br ? cs_w : ct_w;
        const float* bb = br ? cs_b : ct_b;
        int ibo = br * 32;
        float v = bb[l * 32 + n];
        for (int c = 0; c < 32; ++c) v += in_b[ibo + c] * W[l*2048 + 1024 + c*32 + n]; // cur tap
        if (pvi)
            for (int c = 0; c < 32; ++c) v += in_b[ibo + c] * W[l*2048 + c*32 + n];    // prev tap
        BIAS[e] = v;
    }
}

// ---------------------------------------------------------------------------
// Fused net. One block per (b,t), XCD-swizzled so XCD j owns batch j (X slab
// fits its 4MB L2). All 5 conv slabs (4 prev + cur) pre-staged into Pld in
// one load burst at block start -> zero global X traffic inside the loop.
// Layer body reordered: publish -> barrier -> conv MFMA || A-mix MFMA ||
// ts_act VALU, so the exp chain hides under independent MFMAs.
// ---------------------------------------------------------------------------
__global__ __launch_bounds__(256, 3) void k_fused(
    const float* __restrict__ X,
    const _Float16* __restrict__ FR,
    const float* __restrict__ BIAS,
    const float* __restrict__ in_b,
    const float* __restrict__ gcn_b,
    const float* __restrict__ res_b,
    const float* __restrict__ skip_b,
    const float* __restrict__ b1,
    const float* __restrict__ b2,
    float* __restrict__ out)
{
    __shared__ _Float16 Pld[128 * 88];        // [node][p0|p1|p2|p3|cur|pad8], stride 88
    __shared__ _Float16 xsT[2][32 * 136];     // [chan][node(128)+pad8], ping-pong

    const int bx = blockIdx.x;
    const int btid = ((bx & 7) << 9) | (bx >> 3);   // XCD j <- batch j
    const int b = btid >> 9, t = btid & (T_ - 1);
    const int tid = threadIdx.x, lane = tid & 63, w = tid >> 6;
    const int lm = lane & 15, kb = lane >> 4;
    const int R = w * 32;
    const int row = lane >> 1, ch = lane & 1;

    const half8* AFv  = (const half8*)FR;
    const half8* W32v = (const half8*)(FR + 16384);
    const half4* W16v = (const half4*)(FR + 24576);
    const f32x4 zero4 = {0.f, 0.f, 0.f, 0.f};

    // ---- stage ALL conv slabs up-front (one load burst, max MLP) ----
    {
        const size_t nrow = (size_t)(b * 128 + R + row) * T_;
        const float4* xc = (const float4*)(X + (nrow + t) * 16 + ch * 8);
        float4 c0 = xc[0], c1 = xc[1];
        float4 p0[4], p1[4];
#pragma unroll
        for (int l = 0; l < 4; ++l) {
            const int d = 1 << l;
            if (t >= d) {
                const float4* xp = (const float4*)(X + (nrow + (t - d)) * 16 + ch * 8);
                p0[l] = xp[0]; p1[l] = xp[1];
            } else {
                p0[l] = make_float4(0.f, 0.f, 0.f, 0.f);
                p1[l] = make_float4(0.f, 0.f, 0.f, 0.f);
            }
        }
        half8 hv;
        hv[0]=(_Float16)c0.x; hv[1]=(_Float16)c0.y; hv[2]=(_Float16)c0.z; hv[3]=(_Float16)c0.w;
        hv[4]=(_Float16)c1.x; hv[5]=(_Float16)c1.y; hv[6]=(_Float16)c1.z; hv[7]=(_Float16)c1.w;
        *(half8*)&Pld[(R + row) * 88 + 64 + ch * 8] = hv;
#pragma unroll
        for (int l = 0; l < 4; ++l) {
            hv[0]=(_Float16)p0[l].x; hv[1]=(_Float16)p0[l].y; hv[2]=(_Float16)p0[l].z; hv[3]=(_Float16)p0[l].w;
            hv[4]=(_Float16)p1[l].x; hv[5]=(_Float16)p1[l].y; hv[6]=(_Float16)p1[l].z; hv[7]=(_Float16)p1[l].w;
            *(half8*)&Pld[(R + row) * 88 + l * 16 + ch * 8] = hv;
        }
    }

    // ---- xres init: K=16 MFMA straight from registers (true coords) ----
    f32x4 xm[2][2], skT[2][2];
    {
        const float4 x0 = *(const float4*)(X + ((size_t)btid * 128 + R + lm) * 16 + kb * 4);
        const float4 x1 = *(const float4*)(X + ((size_t)btid * 128 + R + 16 + lm) * 16 + kb * 4);
        half4 p0, p1;
        p0[0]=(_Float16)x0.x; p0[1]=(_Float16)x0.y; p0[2]=(_Float16)x0.z; p0[3]=(_Float16)x0.w;
        p1[0]=(_Float16)x1.x; p1[1]=(_Float16)x1.y; p1[2]=(_Float16)x1.z; p1[3]=(_Float16)x1.w;
#pragma unroll
        for (int f = 0; f < 2; ++f) {
            half4 wi = W16v[(56 + f) * 64 + lane];          // winit mat 14, ks=0
            float bi = in_b[64 + f * 16 + lm];
            f32x4 cb; cb[0] = bi; cb[1] = bi; cb[2] = bi; cb[3] = bi;
            xm[0][f] = __builtin_amdgcn_mfma_f32_16x16x16f16(p0, wi, cb, 0, 0, 0);
            xm[1][f] = __builtin_amdgcn_mfma_f32_16x16x16f16(p1, wi, cb, 0, 0, 0);
        }
        // skip accumulator starts at sum_l skip_b (replaces per-layer adds)
#pragma unroll
        for (int f3 = 0; f3 < 2; ++f3) {
            f32x4 s = zero4;
#pragma unroll
            for (int l = 0; l < 4; ++l) {
                const float4 q = *(const float4*)&skip_b[l * 32 + f3 * 16 + kb * 4];
                s[0] += q.x; s[1] += q.y; s[2] += q.z; s[3] += q.w;
            }
            skT[f3][0] = s; skT[f3][1] = s;
        }
    }

    // per-lane conv fragment offset: kb<2 -> prev slab l (halves l*16+kb*8),
    // kb>=2 -> cur slab (halves 64+(kb-2)*8)
    const int fragoff = (kb < 2) ? kb * 8 : 64 + (kb - 2) * 8;
    const int lstep   = (kb < 2) ? 16 : 0;

#pragma unroll 1
    for (int l = 0; l < 4; ++l) {
        const bool pv = (t >= (1 << l));          // block-uniform
        const float* B2 = BIAS + (l * 2 + (pv ? 1 : 0)) * 64;
        const int buf = l & 1;

        // ---- publish xres (normal D -> chan-major LDS) ----
#pragma unroll
        for (int mt = 0; mt < 2; ++mt)
#pragma unroll
            for (int f = 0; f < 2; ++f)
                *(half4*)&xsT[buf][(f * 16 + lm) * 136 + R + mt * 16 + kb * 4] = pack4(xm[mt][f]);

        // ---- prefetch (latency drains at the barrier) ----
        half8 Afr[2][4];
#pragma unroll
        for (int mt = 0; mt < 2; ++mt)
#pragma unroll
            for (int kt = 0; kt < 4; ++kt)
                Afr[mt][kt] = AFv[((w * 2 + mt) * 4 + kt) * 64 + lane];
        const f32x4 cT0 = *(const f32x4*)&B2[0 * 16 + kb * 4];
        const f32x4 cT1 = *(const f32x4*)&B2[1 * 16 + kb * 4];
        const f32x4 cS0 = *(const f32x4*)&B2[32 + 0 * 16 + kb * 4];
        const f32x4 cS1 = *(const f32x4*)&B2[32 + 1 * 16 + kb * 4];

        __syncthreads();

        // ---- conv MFMAs (raw outputs kept; act deferred past A-mix) ----
        const int poff = fragoff + l * lstep;
        half8 pf0 = *(const half8*)&Pld[(R + lm) * 88 + poff];
        half8 pf1 = *(const half8*)&Pld[(R + 16 + lm) * 88 + poff];
        f32x4 dt[2][2], ds[2][2];                 // [ct][mt]
#pragma unroll
        for (int ct = 0; ct < 2; ++ct) {
            half8 wt = W32v[((l * 2 + 0) * 2 + ct) * 64 + lane];
            half8 ws = W32v[((l * 2 + 1) * 2 + ct) * 64 + lane];
            const f32x4 cT = ct ? cT1 : cT0;
            const f32x4 cS = ct ? cS1 : cS0;
            dt[ct][0] = __builtin_amdgcn_mfma_f32_16x16x32_f16(wt, pf0, cT, 0, 0, 0);
            dt[ct][1] = __builtin_amdgcn_mfma_f32_16x16x32_f16(wt, pf1, cT, 0, 0, 0);
            ds[ct][0] = __builtin_amdgcn_mfma_f32_16x16x32_f16(ws, pf0, cS, 0, 0, 0);
            ds[ct][1] = __builtin_amdgcn_mfma_f32_16x16x32_f16(ws, pf1, cS, 0, 0, 0);
        }

        // ---- A-mix: AxT[c][i] — A = xres^T frags (LDS), B = adjacency frags ----
        f32x4 AxT[2][2];                          // [f][mt]
#pragma unroll
        for (int f = 0; f < 2; ++f) {
            half8 xa[4];
#pragma unroll
            for (int kt = 0; kt < 4; ++kt)
                xa[kt] = *(const half8*)&xsT[buf][(f * 16 + lm) * 136 + kt * 32 + kb * 8];
#pragma unroll
            for (int mt = 0; mt < 2; ++mt) {
                f32x4 acc = zero4;
#pragma unroll
                for (int kt = 0; kt < 4; ++kt)
                    acc = __builtin_amdgcn_mfma_f32_16x16x32_f16(xa[kt], Afr[mt][kt], acc, 0, 0, 0);
                AxT[f][mt] = acc;
            }
        }

        // ---- ts_act (exp chain overlaps A-mix MFMAs above) ----
        f32x4 tcv[2][2];                          // [ct][mt]
#pragma unroll
        for (int ct = 0; ct < 2; ++ct)
#pragma unroll
            for (int mt = 0; mt < 2; ++mt)
#pragma unroll
                for (int r = 0; r < 4; ++r)
                    tcv[ct][mt][r] = ts_act(dt[ct][mt][r], ds[ct][mt][r]);

        // ---- gcn_T: gcn_b rides C; add tcv after ----
        half4 axh[2][2];
#pragma unroll
        for (int f = 0; f < 2; ++f)
#pragma unroll
            for (int mt = 0; mt < 2; ++mt) axh[f][mt] = pack4(AxT[f][mt]);
        half4 hh[2][2];                           // h_T packed [g][mt]
#pragma unroll
        for (int g = 0; g < 2; ++g) {
            half4 gw0 = W16v[((l * 3 + 0) * 4 + 0 + g) * 64 + lane];
            half4 gw1 = W16v[((l * 3 + 0) * 4 + 2 + g) * 64 + lane];
            const f32x4 gq = *(const f32x4*)&gcn_b[l * 32 + g * 16 + kb * 4];
#pragma unroll
            for (int mt = 0; mt < 2; ++mt) {
                f32x4 acc = __builtin_amdgcn_mfma_f32_16x16x16f16(gw0, axh[0][mt], gq, 0, 0, 0);
                acc = __builtin_amdgcn_mfma_f32_16x16x16f16(gw1, axh[1][mt], acc, 0, 0, 0);
#pragma unroll
                for (int r = 0; r < 4; ++r) acc[r] += tcv[g][mt][r];
                hh[g][mt] = pack4(acc);
            }
        }

        // ---- res (normal) & skip_T (bias pre-folded into skT init) ----
#pragma unroll
        for (int mt = 0; mt < 2; ++mt)
#pragma unroll
            for (int f3 = 0; f3 < 2; ++f3) {
                half4 rw0 = W16v[((l * 3 + 1) * 4 + 0 + f3) * 64 + lane];
                half4 rw1 = W16v[((l * 3 + 1) * 4 + 2 + f3) * 64 + lane];
                f32x4 acc = __builtin_amdgcn_mfma_f32_16x16x16f16(hh[0][mt], rw0, xm[mt][f3], 0, 0, 0);
                xm[mt][f3] = __builtin_amdgcn_mfma_f32_16x16x16f16(hh[1][mt], rw1, acc, 0, 0, 0);
                float rb = res_b[l * 32 + f3 * 16 + lm];
#pragma unroll
                for (int r = 0; r < 4; ++r) xm[mt][f3][r] += rb;

                half4 sw0 = W16v[((l * 3 + 2) * 4 + 0 + f3) * 64 + lane];
                half4 sw1 = W16v[((l * 3 + 2) * 4 + 2 + f3) * 64 + lane];
                f32x4 acs = __builtin_amdgcn_mfma_f32_16x16x16f16(sw0, hh[0][mt], skT[f3][mt], 0, 0, 0);
                skT[f3][mt] = __builtin_amdgcn_mfma_f32_16x16x16f16(sw1, hh[1][mt], acs, 0, 0, 0);
            }
    }

    // ---- output head (biases ride C operands) ----
    half4 rs[2][2];
#pragma unroll
    for (int g = 0; g < 2; ++g)
#pragma unroll
        for (int mt = 0; mt < 2; ++mt) {
            f32x4 v;
#pragma unroll
            for (int r = 0; r < 4; ++r) v[r] = fmaxf(skT[g][mt][r], 0.f);
            rs[g][mt] = pack4(v);
        }
    half4 h1h[2][2];
#pragma unroll
    for (int g4 = 0; g4 < 2; ++g4) {
        half4 w10 = W16v[(48 + 0 + g4) * 64 + lane];
        half4 w11 = W16v[(48 + 2 + g4) * 64 + lane];
        const f32x4 bq = *(const f32x4*)&b1[g4 * 16 + kb * 4];
#pragma unroll
        for (int mt = 0; mt < 2; ++mt) {
            f32x4 acc = __builtin_amdgcn_mfma_f32_16x16x16f16(w10, rs[0][mt], bq, 0, 0, 0);
            acc = __builtin_amdgcn_mfma_f32_16x16x16f16(w11, rs[1][mt], acc, 0, 0, 0);
            f32x4 v;
#pragma unroll
            for (int r = 0; r < 4; ++r) v[r] = fmaxf(acc[r], 0.f);
            h1h[g4][mt] = pack4(v);
        }
    }
    {
        half4 w20 = W16v[(52 + 0) * 64 + lane];
        half4 w21 = W16v[(52 + 2) * 64 + lane];
        const f32x4 b2q = *(const f32x4*)&b2[kb * 4];
#pragma unroll
        for (int mt = 0; mt < 2; ++mt) {
            f32x4 acc = __builtin_amdgcn_mfma_f32_16x16x16f16(w20, h1h[0][mt], b2q, 0, 0, 0);
            acc = __builtin_amdgcn_mfma_f32_16x16x16f16(w21, h1h[1][mt], acc, 0, 0, 0);
            float4 o = make_float4(acc[0], acc[1], acc[2], acc[3]);
            *(float4*)&out[((size_t)btid * 128 + R + mt * 16 + lm) * 16 + kb * 4] = o;
        }
    }
}

// ---------------------------------------------------------------------------
extern "C" void kernel_launch(void* const* d_in, const int* in_sizes, int n_in,
                              void* d_out, int out_size, void* d_ws, size_t ws_size,
                              hipStream_t stream)
{
    const float* X      = (const float*)d_in[0];
    const float* A      = (const float*)d_in[1];
    const float* in_w   = (const float*)d_in[2];
    const float* in_b   = (const float*)d_in[3];
    const float* ct_w   = (const float*)d_in[4];
    const float* ct_b   = (const float*)d_in[5];
    const float* cs_w   = (const float*)d_in[6];
    const float* cs_b   = (const float*)d_in[7];
    const float* gcn_w  = (const float*)d_in[8];
    const float* gcn_b  = (const float*)d_in[9];
    const float* res_w  = (const float*)d_in[10];
    const float* res_b  = (const float*)d_in[11];
    const float* skip_w = (const float*)d_in[12];
    const float* skip_b = (const float*)d_in[13];
    const float* out1_w = (const float*)d_in[14];
    const float* out1_b = (const float*)d_in[15];
    const float* out2_w = (const float*)d_in[16];
    const float* out2_b = (const float*)d_in[17];

    _Float16* FR   = (_Float16*)d_ws;                 // 39936 f16 = 79872 B
    float*    BIAS = (float*)((char*)d_ws + 79872);   // 512 f32

    k_prep<<<158, 256, 0, stream>>>(A, in_w, in_b, ct_w, ct_b, cs_w, cs_b,
                                    gcn_w, res_w, skip_w, out1_w, out2_w,
                                    FR, BIAS);

    k_fused<<<8 * T_, 256, 0, stream>>>(X, FR, BIAS, in_b,
                                        gcn_b, res_b, skip_b,
                                        out1_b, out2_b, (float*)d_out);
}